// Round 4
// baseline (2845.684 us; speedup 1.0000x reference)
//
#include <hip/hip_runtime.h>
#include <hip/hip_bf16.h>

#define N_NODESC 100000
#define N_EDGESC 250000
#define EMB 300
#define LD 304      // fp32 h / etab stride (float4-friendly)
#define LD4 76
#define LAYERS 5
#define BN_EPS 1e-5f

#define K1 320      // padded K for GEMM1 (agg stride)
#define N1 640      // padded N for GEMM1 (= K for GEMM2)
#define K2 640
#define N2 384      // padded N for GEMM2 (output guarded to 300)

#define NB_SCAN 391 // ceil(100000/256)
#define BM 64       // fused block row-tile

// LDS layout (bytes): As 40960 | Hs 81920 | Bs 2x16384 | red 512
#define LDS_AS   0
#define LDS_HS   40960
#define LDS_BS   (40960 + 81920)
#define LDS_RED  (40960 + 81920 + 32768)
#define LDS_TOT  (40960 + 81920 + 32768 + 512)

typedef __attribute__((ext_vector_type(8))) short short8;
typedef __attribute__((ext_vector_type(4))) float f32x4;

#define GLOAD16(g, l) __builtin_amdgcn_global_load_lds( \
    (const __attribute__((address_space(1))) void*)(g), \
    (__attribute__((address_space(3))) void*)(l), 16, 0, 0)

__device__ __forceinline__ float4 f4add(float4 a, float4 b){
    return make_float4(a.x+b.x, a.y+b.y, a.z+b.z, a.w+b.w);
}
__device__ __forceinline__ unsigned short f2bf(float f){
    __hip_bfloat16 h = __float2bfloat16(f);
    return *(unsigned short*)&h;
}

// ---------------- utility zero kernels --------------------------------------
__global__ void k_zero_i(int* p, int n){
    int i = blockIdx.x*blockDim.x + threadIdx.x;
    if(i < n) p[i] = 0;
}
__global__ void k_zero_f(float* p, int n){
    int i = blockIdx.x*blockDim.x + threadIdx.x;
    if(i < n) p[i] = 0.f;
}

// ---------------- atom encoder: h = emb1[x0] + emb2[x1], fp32 stride LD -----
__global__ void k_atom(const int* __restrict__ x,
                       const float* __restrict__ e1,
                       const float* __restrict__ e2,
                       float* __restrict__ h){
    int idx = blockIdx.x*blockDim.x + threadIdx.x;
    if(idx >= N_NODESC*LD4) return;
    int i = idx / LD4, c = idx % LD4;
    float4 v = make_float4(0,0,0,0);
    if(c < 75){
        int i0 = x[2*i], i1 = x[2*i+1];
        const float4* r1 = (const float4*)(e1 + (size_t)i0*EMB);
        const float4* r2 = (const float4*)(e2 + (size_t)i1*EMB);
        v = f4add(r1[c], r2[c]);
    }
    ((float4*)h)[idx] = v;
}

// ---------------- combined edge-embedding table etab[l][ea0*3+ea1][LD] ------
__global__ void k_etab(const float* __restrict__ e1,
                       const float* __restrict__ e2,
                       float* __restrict__ etab){
    int idx = blockIdx.x*blockDim.x + threadIdx.x;
    if(idx >= LAYERS*18*LD4) return;
    int l = idx / (18*LD4);
    int r = idx % (18*LD4);
    int c = r / LD4, f = r % LD4;
    float4 v = make_float4(0,0,0,0);
    if(f < 75){
        const float4* r1 = (const float4*)(e1 + (size_t)(l*6 + c/3)*EMB);
        const float4* r2 = (const float4*)(e2 + (size_t)(l*3 + c%3)*EMB);
        v = f4add(r1[f], r2[f]);
    }
    ((float4*)etab)[idx] = v;
}

// ---------------- weight prep: B^T padded bf16 ------------------------------
__global__ void k_prepw1(const float* __restrict__ W1, unsigned short* __restrict__ wb){
    int idx = blockIdx.x*blockDim.x + threadIdx.x;
    if(idx >= LAYERS*N1*K1) return;
    int l = idx / (N1*K1);
    int r = idx % (N1*K1);
    int n = r / K1, k = r % K1;
    float v = (n < 600 && k < EMB) ? W1[((size_t)l*EMB + k)*600 + n] : 0.f;
    wb[idx] = f2bf(v);
}
__global__ void k_prepw2(const float* __restrict__ W2, unsigned short* __restrict__ wb){
    int idx = blockIdx.x*blockDim.x + threadIdx.x;
    if(idx >= LAYERS*N2*K2) return;
    int l = idx / (N2*K2);
    int r = idx % (N2*K2);
    int n = r / K2, k = r % K2;
    float v = (n < EMB && k < 600) ? W2[((size_t)l*600 + k)*EMB + n] : 0.f;
    wb[idx] = f2bf(v);
}
__global__ void k_prepb1(const float* __restrict__ b1, float* __restrict__ bp){
    int idx = blockIdx.x*blockDim.x + threadIdx.x;
    if(idx >= LAYERS*N1) return;
    int l = idx / N1, n = idx % N1;
    bp[idx] = (n < 600) ? b1[(size_t)l*600 + n] : 0.f;
}

// ---------------- CSR build -------------------------------------------------
__global__ void k_deg(const int* __restrict__ ei, int* __restrict__ deg){
    int e = blockIdx.x*blockDim.x + threadIdx.x;
    if(e >= N_EDGESC) return;
    atomicAdd(&deg[ei[N_EDGESC + e]], 1);
}

__global__ void k_bsum(const int* __restrict__ deg, int* __restrict__ bsum){
    int g = blockIdx.x*256 + threadIdx.x;
    int v = (g < N_NODESC) ? deg[g] : 0;
    #pragma unroll
    for(int o=32;o>0;o>>=1) v += __shfl_down(v, o);
    __shared__ int sw[4];
    if((threadIdx.x & 63) == 0) sw[threadIdx.x>>6] = v;
    __syncthreads();
    if(threadIdx.x == 0) bsum[blockIdx.x] = sw[0]+sw[1]+sw[2]+sw[3];
}

__global__ void k_bscan(const int* __restrict__ bsum, int* __restrict__ bpre,
                        int* __restrict__ offs){
    __shared__ int sh[512];
    int t = threadIdx.x;
    int v = (t < NB_SCAN) ? bsum[t] : 0;
    sh[t] = v; __syncthreads();
    for(int o=1;o<512;o<<=1){
        int u = (t >= o) ? sh[t-o] : 0;
        __syncthreads();
        sh[t] += u;
        __syncthreads();
    }
    if(t < NB_SCAN) bpre[t] = sh[t] - v;
    if(t == NB_SCAN-1) offs[N_NODESC] = sh[t];
}

__global__ void k_offs(const int* __restrict__ deg, const int* __restrict__ bpre,
                       int* __restrict__ offs, int* __restrict__ cursor){
    __shared__ int sh[256];
    int t = threadIdx.x;
    int g = blockIdx.x*256 + t;
    int v = (g < N_NODESC) ? deg[g] : 0;
    sh[t] = v; __syncthreads();
    for(int o=1;o<256;o<<=1){
        int u = (t >= o) ? sh[t-o] : 0;
        __syncthreads();
        sh[t] += u;
        __syncthreads();
    }
    if(g < N_NODESC){
        int e = bpre[blockIdx.x] + sh[t] - v;
        offs[g] = e; cursor[g] = e;
    }
}

__global__ void k_fill(const int* __restrict__ ei, const int* __restrict__ ea,
                       int* __restrict__ cursor,
                       int* __restrict__ csr_src, int* __restrict__ csr_ea){
    int e = blockIdx.x*blockDim.x + threadIdx.x;
    if(e >= N_EDGESC) return;
    int d = ei[N_EDGESC + e];
    int p = atomicAdd(&cursor[d], 1);
    csr_src[p] = ei[e];
    csr_ea[p]  = ea[2*e]*3 + ea[2*e+1];
}

// ---------------- gather-sum aggregation -> bf16 agg[i][K1] -----------------
__global__ void k_agg(const float* __restrict__ h, const float* __restrict__ etab_l,
                      const int* __restrict__ offs, const int* __restrict__ csr_src,
                      const int* __restrict__ csr_ea, unsigned short* __restrict__ agg){
    int idx = blockIdx.x*blockDim.x + threadIdx.x;
    if(idx >= N_NODESC*80) return;
    int i = idx / 80, c = idx % 80;
    ushort4 out;
    if(c < 75){
        const float4* h4 = (const float4*)h;
        const float4* et = (const float4*)etab_l;
        float4 acc = f4add(h4[(size_t)i*LD4 + c], et[12*LD4 + c]);
        int j0 = offs[i], j1 = offs[i+1];
        for(int j=j0; j<j1; j++){
            int s = csr_src[j];
            int t = csr_ea[j];
            acc = f4add(acc, f4add(h4[(size_t)s*LD4 + c], et[t*LD4 + c]));
        }
        out.x = f2bf(acc.x); out.y = f2bf(acc.y);
        out.z = f2bf(acc.z); out.w = f2bf(acc.w);
    } else {
        out.x = out.y = out.z = out.w = 0;
    }
    *(ushort4*)(agg + (size_t)i*K1 + c*4) = out;
}

// ---------------- fused layer GEMM: dout = (relu(agg@W1+b1))@W2 + b2 --------
// Per block: 64 rows. Phase A: hmid panel [64][640] bf16 -> LDS (swizzled).
// Phase B: out [64][384->300] fp32 + fused BN stats.
// All LDS tiles chunk-swizzled: physical_chunk = logical_chunk ^ (row & 7).
__global__ __launch_bounds__(256) void k_fused(
    const unsigned short* __restrict__ agg,   // [N][K1]
    const unsigned short* __restrict__ w1t,   // [N1][K1]
    const unsigned short* __restrict__ w2t,   // [N2][K2]
    const float* __restrict__ bias1,          // [N1] (padded)
    const float* __restrict__ bias2,          // [EMB]
    float* __restrict__ out,                  // [N][EMB]
    float* __restrict__ stats)                // [2*EMB]
{
    extern __shared__ char smem[];
    unsigned short* As = (unsigned short*)(smem + LDS_AS);   // [64][320]
    unsigned short* Hs = (unsigned short*)(smem + LDS_HS);   // [64][640]
    unsigned short* Bs = (unsigned short*)(smem + LDS_BS);   // 2 x [128][64]
    float*          red = (float*)(smem + LDS_RED);          // [4][16][2]

    const int tid = threadIdx.x;
    const int wv = tid >> 6, ln = tid & 63;
    const int wr = wv >> 1, wc = wv & 1;
    const int lr = ln & 15, hi = ln >> 4;
    const int m0 = blockIdx.x * BM;

    // ---- prologue: stage A tile (64 rows x 40 chunks, swizzled source) -----
    #pragma unroll
    for(int i=0;i<10;i++){
        int id = i*256 + tid;
        int row = id / 40, cp = id % 40;
        int gr = m0 + row; if(gr >= N_NODESC) gr = N_NODESC-1;
        const unsigned short* src = agg + (size_t)gr*K1 + ((cp ^ (row&7))<<3);
        GLOAD16(src, (char*)As + id*16);
    }
    // ---- stage first W tile (phase A, nc=0, kc=0) into buf 0 ----------------
    {
        #pragma unroll
        for(int i=0;i<4;i++){
            int id = i*256 + tid;
            int row = id >> 3, cp = id & 7;
            const unsigned short* src = w1t + (size_t)row*K1 + ((cp ^ (row&7))<<3);
            GLOAD16(src, (char*)Bs + id*16);
        }
    }

    int pb = 0;
    f32x4 acc[2][4];

    // 55 steps: s<25 -> phase A (nc=s/5, kc=s%5), else phase B ((s-25)/10, %10)
    for(int s=0; s<55; s++){
        __syncthreads();   // drains vmem (staged tiles) + lds ops

        // ---- prefetch step s+1's W tile into buf pb^1 -----------------------
        if(s+1 < 55){
            int s1 = s+1;
            const unsigned short* Wt; int n0w, kc1, Kd;
            if(s1 < 25){ Wt = w1t; n0w = (s1/5)*128;      kc1 = s1%5;      Kd = K1; }
            else       { Wt = w2t; n0w = ((s1-25)/10)*128; kc1 = (s1-25)%10; Kd = K2; }
            char* dst = (char*)Bs + (pb^1)*16384;
            #pragma unroll
            for(int i=0;i<4;i++){
                int id = i*256 + tid;
                int row = id >> 3, cp = id & 7;
                const unsigned short* src = Wt + (size_t)(n0w + row)*Kd
                                            + kc1*64 + ((cp ^ (row&7))<<3);
                GLOAD16(src, dst + id*16);
            }
        }

        const bool phaseA = (s < 25);
        const int kc = phaseA ? (s % 5) : ((s-25) % 10);
        const int nc = phaseA ? (s / 5) : ((s-25) / 10);

        if(kc == 0){
            #pragma unroll
            for(int m=0;m<2;m++)
                #pragma unroll
                for(int n=0;n<4;n++) acc[m][n] = (f32x4){0.f,0.f,0.f,0.f};
        }

        // ---- compute step s from buf pb ------------------------------------
        const unsigned short* Bp = Bs + pb*8192;
        #pragma unroll
        for(int ks=0; ks<2; ks++){
            short8 av[2], bv[4];
            int k0 = kc*64 + ks*32 + hi*8;
            int cA = k0 >> 3;
            if(phaseA){
                #pragma unroll
                for(int m=0;m<2;m++){
                    int row = wr*32 + m*16 + lr;
                    av[m] = *(const short8*)(As + row*320 + ((cA ^ (row&7))<<3));
                }
            } else {
                #pragma unroll
                for(int m=0;m<2;m++){
                    int row = wr*32 + m*16 + lr;
                    av[m] = *(const short8*)(Hs + row*640 + ((cA ^ (row&7))<<3));
                }
            }
            int cB = (ks*32 + hi*8) >> 3;
            #pragma unroll
            for(int n=0;n<4;n++){
                int row = wc*64 + n*16 + lr;
                bv[n] = *(const short8*)(Bp + row*64 + ((cB ^ (row&7))<<3));
            }
            #pragma unroll
            for(int m=0;m<2;m++)
                #pragma unroll
                for(int n=0;n<4;n++)
                    acc[m][n] = __builtin_amdgcn_mfma_f32_16x16x32_bf16(
                                    av[m], bv[n], acc[m][n], 0, 0, 0);
        }

        // ---- epilogues ------------------------------------------------------
        if(phaseA && kc == 4){
            // hmid panel: relu(acc + b1) -> bf16 -> Hs (swizzled), cols nc*128..
            #pragma unroll
            for(int n=0;n<4;n++){
                int col = nc*128 + wc*64 + n*16 + lr;
                float bsv = bias1[col];
                #pragma unroll
                for(int m=0;m<2;m++){
                    int rb = wr*32 + m*16 + hi*4;
                    #pragma unroll
                    for(int j=0;j<4;j++){
                        int r = rb + j;
                        float v = fmaxf(acc[m][n][j] + bsv, 0.f);
                        int ch = col >> 3, wi = col & 7;
                        Hs[(size_t)r*640 + ((ch ^ (r&7))<<3) + wi] = f2bf(v);
                    }
                }
            }
        }
        if(!phaseA && kc == 9){
            // out writes + BN stats, cols nc*128.., guard col<300, row<N
            #pragma unroll
            for(int n=0;n<4;n++){
                int col = nc*128 + wc*64 + n*16 + lr;
                bool cok = (col < EMB);
                float bsv = cok ? bias2[col] : 0.f;
                float sS = 0.f, sQ = 0.f;
                #pragma unroll
                for(int m=0;m<2;m++){
                    int rb = m0 + wr*32 + m*16 + hi*4;
                    #pragma unroll
                    for(int j=0;j<4;j++){
                        int row = rb + j;
                        if(cok && row < N_NODESC){
                            float v = acc[m][n][j] + bsv;
                            out[(size_t)row*EMB + col] = v;
                            sS += v; sQ += v*v;
                        }
                    }
                }
                sS += __shfl_xor(sS, 16); sQ += __shfl_xor(sQ, 16);
                sS += __shfl_xor(sS, 32); sQ += __shfl_xor(sQ, 32);
                if(hi == 0){ red[(wv*16+lr)*2] = sS; red[(wv*16+lr)*2+1] = sQ; }
                __syncthreads();
                if(wv < 2 && ln < 16){
                    float S = red[(wv*16+ln)*2]   + red[((wv^2)*16+ln)*2];
                    float Q = red[(wv*16+ln)*2+1] + red[((wv^2)*16+ln)*2+1];
                    int c2 = nc*128 + wv*64 + n*16 + ln;
                    if(c2 < EMB){
                        atomicAdd(&stats[c2], S);
                        atomicAdd(&stats[EMB + c2], Q);
                    }
                }
                __syncthreads();
            }
        }
        pb ^= 1;
    }
}

// ---------------- BN apply (+relu) ------------------------------------------
__global__ void k_bnapply(const float* __restrict__ X, const float* __restrict__ stats,
                          const float* __restrict__ g, const float* __restrict__ bt,
                          float* __restrict__ hn, float* __restrict__ dout,
                          int relu, int last){
    int idx = blockIdx.x*blockDim.x + threadIdx.x;
    if(idx >= N_NODESC*LD4) return;
    int i = idx / LD4, c = idx % LD4;
    if(c == 75){
        if(!last) ((float4*)hn)[idx] = make_float4(0,0,0,0);
        return;
    }
    const float4* X4 = (const float4*)X;
    float4 v  = X4[(size_t)i*75 + c];
    float4 s  = ((const float4*)stats)[c];
    float4 q  = ((const float4*)stats)[75 + c];
    float4 gg = ((const float4*)g)[c];
    float4 bb = ((const float4*)bt)[c];
    const float inv_n = 1.0f/(float)N_NODESC;
    #define BN1(f) { float m = s.f*inv_n; float var = q.f*inv_n - m*m;          \
                     float r = rsqrtf(var + BN_EPS);                             \
                     v.f = (v.f - m)*r*gg.f + bb.f;                              \
                     if(relu) v.f = fmaxf(v.f, 0.f); }
    BN1(x) BN1(y) BN1(z) BN1(w)
    #undef BN1
    if(last) ((float4*)dout)[(size_t)i*75 + c] = v;
    else     ((float4*)hn)[idx] = v;
}

// ----------------------------------------------------------------------------
extern "C" void kernel_launch(void* const* d_in, const int* in_sizes, int n_in,
                              void* d_out, int out_size, void* d_ws, size_t ws_size,
                              hipStream_t stream) {
    const int*   x     = (const int*)d_in[0];
    const int*   ei    = (const int*)d_in[1];
    const int*   ea    = (const int*)d_in[2];
    const float* aemb1 = (const float*)d_in[3];
    const float* aemb2 = (const float*)d_in[4];
    const float* eemb1 = (const float*)d_in[5];
    const float* eemb2 = (const float*)d_in[6];
    const float* W1    = (const float*)d_in[7];
    const float* b1    = (const float*)d_in[8];
    const float* W2    = (const float*)d_in[9];
    const float* b2    = (const float*)d_in[10];
    const float* gamma = (const float*)d_in[11];
    const float* beta  = (const float*)d_in[12];
    float* dout = (float*)d_out;

    // workspace layout
    float* h      = (float*)d_ws;                              // 100000*304 f
    float* bias1p = h + (size_t)N_NODESC*LD;                   // 5*640 f
    float* etab   = bias1p + LAYERS*N1;                        // 5*18*304 f
    float* stats  = etab + LAYERS*18*LD;                       // 640 f
    unsigned short* agg  = (unsigned short*)(stats + 640);     // 100000*320 bf16
    unsigned short* wb1t = agg  + (size_t)N_NODESC*K1;         // 5*640*320 bf16
    unsigned short* wb2t = wb1t + (size_t)LAYERS*N1*K1;        // 5*384*640 bf16
    int*   deg     = (int*)(wb2t + (size_t)LAYERS*N2*K2);
    int*   offs    = deg    + N_NODESC;
    int*   cursor  = offs   + N_NODESC + 1;
    int*   csr_src = cursor + N_NODESC + 1;
    int*   csr_ea  = csr_src + N_EDGESC;
    int*   bsum    = csr_ea + N_EDGESC;
    int*   bpre    = bsum + NB_SCAN;

    const int nb_nf4 = (N_NODESC*LD4 + 255)/256;

    // allow >64KB dynamic LDS for the fused kernel
    hipFuncSetAttribute((const void*)k_fused,
                        hipFuncAttributeMaxDynamicSharedMemorySize, LDS_TOT);

    // one-time setup
    k_atom<<<nb_nf4, 256, 0, stream>>>(x, aemb1, aemb2, h);
    k_etab<<<(LAYERS*18*LD4 + 255)/256, 256, 0, stream>>>(eemb1, eemb2, etab);
    k_prepw1<<<(LAYERS*N1*K1 + 255)/256, 256, 0, stream>>>(W1, wb1t);
    k_prepw2<<<(LAYERS*N2*K2 + 255)/256, 256, 0, stream>>>(W2, wb2t);
    k_prepb1<<<(LAYERS*N1 + 255)/256, 256, 0, stream>>>(b1, bias1p);
    k_zero_i<<<(N_NODESC + 255)/256, 256, 0, stream>>>(deg, N_NODESC);
    k_deg<<<(N_EDGESC + 255)/256, 256, 0, stream>>>(ei, deg);
    k_bsum<<<NB_SCAN, 256, 0, stream>>>(deg, bsum);
    k_bscan<<<1, 512, 0, stream>>>(bsum, bpre, offs);
    k_offs<<<NB_SCAN, 256, 0, stream>>>(deg, bpre, offs, cursor);
    k_fill<<<(N_EDGESC + 255)/256, 256, 0, stream>>>(ei, ea, cursor, csr_src, csr_ea);

    const int FB = (N_NODESC + BM - 1)/BM;   // 1563 blocks
    for(int l=0; l<LAYERS; l++){
        k_agg<<<(N_NODESC*80 + 255)/256, 256, 0, stream>>>(
            h, etab + (size_t)l*18*LD, offs, csr_src, csr_ea, agg);
        k_zero_f<<<(2*EMB + 255)/256, 256, 0, stream>>>(stats, 2*EMB);
        k_fused<<<FB, 256, LDS_TOT, stream>>>(
            agg, wb1t + (size_t)l*N1*K1, wb2t + (size_t)l*N2*K2,
            bias1p + (size_t)l*N1, b2 + (size_t)l*EMB,
            dout, stats);
        k_bnapply<<<nb_nf4, 256, 0, stream>>>(dout, stats,
                                              gamma + (size_t)l*EMB, beta + (size_t)l*EMB,
                                              h, dout, (l < LAYERS-1) ? 1 : 0,
                                              (l == LAYERS-1) ? 1 : 0);
    }
}

// Round 5
// 1713.361 us; speedup vs baseline: 1.6609x; 1.6609x over previous
//
#include <hip/hip_runtime.h>
#include <hip/hip_bf16.h>

#define N_NODESC 100000
#define N_EDGESC 250000
#define EMB 300
#define LD 304      // fp32 h / etab stride (float4-friendly)
#define LD4 76
#define LAYERS 5
#define BN_EPS 1e-5f

#define K1 320      // padded K for GEMM1 (agg stride)
#define N1 640      // padded N for GEMM1 (hmid stride, = K for GEMM2)
#define K2 640
#define N2 384      // padded N for GEMM2 (output guarded to 300)

#define NB_SCAN 391 // ceil(100000/256)

typedef __attribute__((ext_vector_type(8))) short short8;
typedef __attribute__((ext_vector_type(4))) float f32x4;

#define GLOAD16(g, l) __builtin_amdgcn_global_load_lds( \
    (const __attribute__((address_space(1))) void*)(g), \
    (__attribute__((address_space(3))) void*)(l), 16, 0, 0)

__device__ __forceinline__ float4 f4add(float4 a, float4 b){
    return make_float4(a.x+b.x, a.y+b.y, a.z+b.z, a.w+b.w);
}
__device__ __forceinline__ unsigned short f2bf(float f){
    __hip_bfloat16 h = __float2bfloat16(f);
    return *(unsigned short*)&h;
}

// ---------------- utility zero kernels --------------------------------------
__global__ void k_zero_i(int* p, int n){
    int i = blockIdx.x*blockDim.x + threadIdx.x;
    if(i < n) p[i] = 0;
}
__global__ void k_zero_f(float* p, int n){
    int i = blockIdx.x*blockDim.x + threadIdx.x;
    if(i < n) p[i] = 0.f;
}

// ---------------- atom encoder: h = emb1[x0] + emb2[x1], fp32 stride LD -----
__global__ void k_atom(const int* __restrict__ x,
                       const float* __restrict__ e1,
                       const float* __restrict__ e2,
                       float* __restrict__ h){
    int idx = blockIdx.x*blockDim.x + threadIdx.x;
    if(idx >= N_NODESC*LD4) return;
    int i = idx / LD4, c = idx % LD4;
    float4 v = make_float4(0,0,0,0);
    if(c < 75){
        int i0 = x[2*i], i1 = x[2*i+1];
        const float4* r1 = (const float4*)(e1 + (size_t)i0*EMB);
        const float4* r2 = (const float4*)(e2 + (size_t)i1*EMB);
        v = f4add(r1[c], r2[c]);
    }
    ((float4*)h)[idx] = v;
}

// ---------------- combined edge-embedding table etab[l][ea0*3+ea1][LD] ------
__global__ void k_etab(const float* __restrict__ e1,
                       const float* __restrict__ e2,
                       float* __restrict__ etab){
    int idx = blockIdx.x*blockDim.x + threadIdx.x;
    if(idx >= LAYERS*18*LD4) return;
    int l = idx / (18*LD4);
    int r = idx % (18*LD4);
    int c = r / LD4, f = r % LD4;
    float4 v = make_float4(0,0,0,0);
    if(f < 75){
        const float4* r1 = (const float4*)(e1 + (size_t)(l*6 + c/3)*EMB);
        const float4* r2 = (const float4*)(e2 + (size_t)(l*3 + c%3)*EMB);
        v = f4add(r1[f], r2[f]);
    }
    ((float4*)etab)[idx] = v;
}

// ---------------- weight prep: B^T padded bf16 ------------------------------
__global__ void k_prepw1(const float* __restrict__ W1, unsigned short* __restrict__ wb){
    int idx = blockIdx.x*blockDim.x + threadIdx.x;
    if(idx >= LAYERS*N1*K1) return;
    int l = idx / (N1*K1);
    int r = idx % (N1*K1);
    int n = r / K1, k = r % K1;
    float v = (n < 600 && k < EMB) ? W1[((size_t)l*EMB + k)*600 + n] : 0.f;
    wb[idx] = f2bf(v);
}
__global__ void k_prepw2(const float* __restrict__ W2, unsigned short* __restrict__ wb){
    int idx = blockIdx.x*blockDim.x + threadIdx.x;
    if(idx >= LAYERS*N2*K2) return;
    int l = idx / (N2*K2);
    int r = idx % (N2*K2);
    int n = r / K2, k = r % K2;
    float v = (n < EMB && k < 600) ? W2[((size_t)l*600 + k)*EMB + n] : 0.f;
    wb[idx] = f2bf(v);
}
__global__ void k_prepb1(const float* __restrict__ b1, float* __restrict__ bp){
    int idx = blockIdx.x*blockDim.x + threadIdx.x;
    if(idx >= LAYERS*N1) return;
    int l = idx / N1, n = idx % N1;
    bp[idx] = (n < 600) ? b1[(size_t)l*600 + n] : 0.f;
}

// ---------------- CSR build -------------------------------------------------
__global__ void k_deg(const int* __restrict__ ei, int* __restrict__ deg){
    int e = blockIdx.x*blockDim.x + threadIdx.x;
    if(e >= N_EDGESC) return;
    atomicAdd(&deg[ei[N_EDGESC + e]], 1);
}

__global__ void k_bsum(const int* __restrict__ deg, int* __restrict__ bsum){
    int g = blockIdx.x*256 + threadIdx.x;
    int v = (g < N_NODESC) ? deg[g] : 0;
    #pragma unroll
    for(int o=32;o>0;o>>=1) v += __shfl_down(v, o);
    __shared__ int sw[4];
    if((threadIdx.x & 63) == 0) sw[threadIdx.x>>6] = v;
    __syncthreads();
    if(threadIdx.x == 0) bsum[blockIdx.x] = sw[0]+sw[1]+sw[2]+sw[3];
}

__global__ void k_bscan(const int* __restrict__ bsum, int* __restrict__ bpre,
                        int* __restrict__ offs){
    __shared__ int sh[512];
    int t = threadIdx.x;
    int v = (t < NB_SCAN) ? bsum[t] : 0;
    sh[t] = v; __syncthreads();
    for(int o=1;o<512;o<<=1){
        int u = (t >= o) ? sh[t-o] : 0;
        __syncthreads();
        sh[t] += u;
        __syncthreads();
    }
    if(t < NB_SCAN) bpre[t] = sh[t] - v;
    if(t == NB_SCAN-1) offs[N_NODESC] = sh[t];
}

__global__ void k_offs(const int* __restrict__ deg, const int* __restrict__ bpre,
                       int* __restrict__ offs, int* __restrict__ cursor){
    __shared__ int sh[256];
    int t = threadIdx.x;
    int g = blockIdx.x*256 + t;
    int v = (g < N_NODESC) ? deg[g] : 0;
    sh[t] = v; __syncthreads();
    for(int o=1;o<256;o<<=1){
        int u = (t >= o) ? sh[t-o] : 0;
        __syncthreads();
        sh[t] += u;
        __syncthreads();
    }
    if(g < N_NODESC){
        int e = bpre[blockIdx.x] + sh[t] - v;
        offs[g] = e; cursor[g] = e;
    }
}

__global__ void k_fill(const int* __restrict__ ei, const int* __restrict__ ea,
                       int* __restrict__ cursor,
                       int* __restrict__ csr_src, int* __restrict__ csr_ea){
    int e = blockIdx.x*blockDim.x + threadIdx.x;
    if(e >= N_EDGESC) return;
    int d = ei[N_EDGESC + e];
    int p = atomicAdd(&cursor[d], 1);
    csr_src[p] = ei[e];
    csr_ea[p]  = ea[2*e]*3 + ea[2*e+1];
}

// ---------------- gather-sum aggregation -> bf16 agg[i][K1] -----------------
__global__ void k_agg(const float* __restrict__ h, const float* __restrict__ etab_l,
                      const int* __restrict__ offs, const int* __restrict__ csr_src,
                      const int* __restrict__ csr_ea, unsigned short* __restrict__ agg){
    int idx = blockIdx.x*blockDim.x + threadIdx.x;
    if(idx >= N_NODESC*80) return;
    int i = idx / 80, c = idx % 80;
    ushort4 out;
    if(c < 75){
        const float4* h4 = (const float4*)h;
        const float4* et = (const float4*)etab_l;
        float4 acc = f4add(h4[(size_t)i*LD4 + c], et[12*LD4 + c]);
        int j0 = offs[i], j1 = offs[i+1];
        for(int j=j0; j<j1; j++){
            int s = csr_src[j];
            int t = csr_ea[j];
            acc = f4add(acc, f4add(h4[(size_t)s*LD4 + c], et[t*LD4 + c]));
        }
        out.x = f2bf(acc.x); out.y = f2bf(acc.y);
        out.z = f2bf(acc.z); out.w = f2bf(acc.w);
    } else {
        out.x = out.y = out.z = out.w = 0;
    }
    *(ushort4*)(agg + (size_t)i*K1 + c*4) = out;
}

// ---------------- bf16 MFMA GEMM: C = epi(A @ Bt^T + bias) ------------------
// A [M][KDIM] bf16, Bt [NX*128][KDIM] bf16.  128x128 tile, 4 waves (2x2),
// wave 64x64 (4x4 frags of 16x16x32), BK=32, double-buffered LDS + 1-deep
// prefetch overlap.  LDS chunk-swizzle: phys_chunk = logical ^ ((row>>1)&3),
// applied to the global SOURCE at staging (dest stays linear) and to the
// ds_read address (rule #21: both-sides-or-neither).
// EPI 0: bf16 store via LDS bounce (coalesced short8), +bias, relu, ldc=640.
// EPI 1: fp32 scalar store, +bias, col<300, fused BN stats.
// Grid: 1-D, bijective XCD chunk mapping (m204), x-major inside a chunk so
// blocks sharing an A-panel run on the same XCD.
template<int EPI, int KS, int NX>
__global__ __launch_bounds__(256) void k_mgemm(
    const unsigned short* __restrict__ A,
    const unsigned short* __restrict__ Bt,
    const float* __restrict__ bias,
    void* __restrict__ Cptr, int M, int ldc,
    float* __restrict__ stats, int nwg)
{
    constexpr int KDIM = KS*32;
    __shared__ unsigned short smem_u[16384];   // 32 KB: 2 x (A 8KB | B 8KB)
    char* smem_c = (char*)smem_u;

    // ---- XCD bijective remap, x-major decomposition ------------------------
    int bid = blockIdx.x;
    int q = nwg >> 3, r = nwg & 7;
    int xcd = bid & 7, lo = bid >> 3;
    int wg = (xcd < r) ? (xcd*(q+1) + lo) : (r*(q+1) + (xcd - r)*q + lo);
    int bx = wg % NX, by = wg / NX;
    int m0 = by*128, n0 = bx*128;

    const int tid = threadIdx.x;
    const int wv = tid >> 6, ln = tid & 63;
    const int wm = (wv >> 1)*64, wn = (wv & 1)*64;
    const int lr = ln & 15, hi = ln >> 4;

    // ---- staging addresses (2 chunks per operand per thread) ---------------
    const int id0 = tid, id1 = tid + 256;
    const int rA0 = id0 >> 2, rA1 = id1 >> 2;      // 0..127
    const int c0 = id0 & 3,  c1 = id1 & 3;         // phys chunk
    int g0 = m0 + rA0; if(g0 >= M) g0 = M-1;
    int g1 = m0 + rA1; if(g1 >= M) g1 = M-1;
    const unsigned short* srcA0 = A + (size_t)g0*KDIM + ((c0 ^ ((rA0>>1)&3))<<3);
    const unsigned short* srcA1 = A + (size_t)g1*KDIM + ((c1 ^ ((rA1>>1)&3))<<3);
    const unsigned short* srcB0 = Bt + (size_t)(n0 + rA0)*KDIM + ((c0 ^ ((rA0>>1)&3))<<3);
    const unsigned short* srcB1 = Bt + (size_t)(n0 + rA1)*KDIM + ((c1 ^ ((rA1>>1)&3))<<3);

    f32x4 acc[4][4] = {};

    // ---- prologue: stage kc=0 into buf 0 -----------------------------------
    GLOAD16(srcA0, smem_c + id0*16);
    GLOAD16(srcA1, smem_c + id1*16);
    GLOAD16(srcB0, smem_c + 8192 + id0*16);
    GLOAD16(srcB1, smem_c + 8192 + id1*16);

    // per-lane ds_read offsets (ushort units), row-constant across kc
    int offA[4], offB[4];
    #pragma unroll
    for(int m=0;m<4;m++){
        int row = wm + m*16 + lr;
        offA[m] = row*32 + ((hi ^ ((row>>1)&3))<<3);
    }
    #pragma unroll
    for(int n=0;n<4;n++){
        int row = wn + n*16 + lr;
        offB[n] = 4096 + row*32 + ((hi ^ ((row>>1)&3))<<3);
    }

    #pragma unroll
    for(int kc=0; kc<KS; kc++){
        __syncthreads();                      // buf[kc&1] ready (vm+lgkm drain)
        if(kc+1 < KS){                        // prefetch next into buf^1
            char* db = smem_c + ((kc+1)&1)*16384;
            GLOAD16(srcA0 + (kc+1)*32, db + id0*16);
            GLOAD16(srcA1 + (kc+1)*32, db + id1*16);
            GLOAD16(srcB0 + (kc+1)*32, db + 8192 + id0*16);
            GLOAD16(srcB1 + (kc+1)*32, db + 8192 + id1*16);
        }
        const unsigned short* bufu = smem_u + (kc&1)*8192;
        short8 av[4], bv[4];
        #pragma unroll
        for(int m=0;m<4;m++) av[m] = *(const short8*)(bufu + offA[m]);
        #pragma unroll
        for(int n=0;n<4;n++) bv[n] = *(const short8*)(bufu + offB[n]);
        #pragma unroll
        for(int m=0;m<4;m++)
            #pragma unroll
            for(int n=0;n<4;n++)
                acc[m][n] = __builtin_amdgcn_mfma_f32_16x16x32_bf16(
                                av[m], bv[n], acc[m][n], 0, 0, 0);
    }

    __syncthreads();   // all MFMA/ds done; LDS free for epilogue reuse

    int rbase = wm + hi*4;
    if(EPI == 0){
        // ---- bounce C tile (bf16) through LDS, coalesced short8 stores -----
        unsigned short* Cs = smem_u;          // [128][128]
        unsigned short* Cb = (unsigned short*)Cptr;
        #pragma unroll
        for(int n=0;n<4;n++){
            int col = wn + n*16 + lr;
            float bsv = bias[n0 + col];
            #pragma unroll
            for(int m=0;m<4;m++){
                #pragma unroll
                for(int j=0;j<4;j++){
                    int row = rbase + m*16 + j;
                    Cs[row*128 + col] = f2bf(fmaxf(acc[m][n][j] + bsv, 0.f));
                }
            }
        }
        __syncthreads();
        #pragma unroll
        for(int i=0;i<8;i++){
            int id = i*256 + tid;
            int rr = id >> 4, ch = id & 15;
            int gr = m0 + rr;
            if(gr < M)
                *(short8*)(Cb + (size_t)gr*ldc + n0 + ch*8) =
                    *(const short8*)(Cs + rr*128 + ch*8);
        }
    } else {
        // ---- fp32 stores + fused BN stats ----------------------------------
        float* Cf = (float*)Cptr;
        float* red = (float*)smem_u;          // 128 floats
        #pragma unroll
        for(int n=0;n<4;n++){
            int col = n0 + wn + n*16 + lr;
            bool cok = (col < EMB);
            float bsv = cok ? bias[col] : 0.f;
            float sS = 0.f, sQ = 0.f;
            #pragma unroll
            for(int m=0;m<4;m++){
                #pragma unroll
                for(int j=0;j<4;j++){
                    int row = m0 + rbase + m*16 + j;
                    if(cok && row < M){
                        float v = acc[m][n][j] + bsv;
                        Cf[(size_t)row*ldc + col] = v;
                        sS += v; sQ += v*v;
                    }
                }
            }
            sS += __shfl_xor(sS, 16); sQ += __shfl_xor(sQ, 16);
            sS += __shfl_xor(sS, 32); sQ += __shfl_xor(sQ, 32);
            if(hi == 0){ red[(wv*16+lr)*2] = sS; red[(wv*16+lr)*2+1] = sQ; }
            __syncthreads();
            if(wv < 2 && ln < 16){
                float S = red[(wv*16+ln)*2]   + red[((wv+2)*16+ln)*2];
                float Q = red[(wv*16+ln)*2+1] + red[((wv+2)*16+ln)*2+1];
                int c2 = n0 + wv*64 + n*16 + ln;
                if(c2 < EMB){
                    atomicAdd(&stats[c2], S);
                    atomicAdd(&stats[EMB + c2], Q);
                }
            }
            __syncthreads();
        }
    }
}

// ---------------- BN apply (+relu) ------------------------------------------
__global__ void k_bnapply(const float* __restrict__ X, const float* __restrict__ stats,
                          const float* __restrict__ g, const float* __restrict__ bt,
                          float* __restrict__ hn, float* __restrict__ dout,
                          int relu, int last){
    int idx = blockIdx.x*blockDim.x + threadIdx.x;
    if(idx >= N_NODESC*LD4) return;
    int i = idx / LD4, c = idx % LD4;
    if(c == 75){
        if(!last) ((float4*)hn)[idx] = make_float4(0,0,0,0);
        return;
    }
    const float4* X4 = (const float4*)X;
    float4 v  = X4[(size_t)i*75 + c];
    float4 s  = ((const float4*)stats)[c];
    float4 q  = ((const float4*)stats)[75 + c];
    float4 gg = ((const float4*)g)[c];
    float4 bb = ((const float4*)bt)[c];
    const float inv_n = 1.0f/(float)N_NODESC;
    #define BN1(f) { float m = s.f*inv_n; float var = q.f*inv_n - m*m;          \
                     float r = rsqrtf(var + BN_EPS);                             \
                     v.f = (v.f - m)*r*gg.f + bb.f;                              \
                     if(relu) v.f = fmaxf(v.f, 0.f); }
    BN1(x) BN1(y) BN1(z) BN1(w)
    #undef BN1
    if(last) ((float4*)dout)[(size_t)i*75 + c] = v;
    else     ((float4*)hn)[idx] = v;
}

// ----------------------------------------------------------------------------
extern "C" void kernel_launch(void* const* d_in, const int* in_sizes, int n_in,
                              void* d_out, int out_size, void* d_ws, size_t ws_size,
                              hipStream_t stream) {
    const int*   x     = (const int*)d_in[0];
    const int*   ei    = (const int*)d_in[1];
    const int*   ea    = (const int*)d_in[2];
    const float* aemb1 = (const float*)d_in[3];
    const float* aemb2 = (const float*)d_in[4];
    const float* eemb1 = (const float*)d_in[5];
    const float* eemb2 = (const float*)d_in[6];
    const float* W1    = (const float*)d_in[7];
    const float* b1    = (const float*)d_in[8];
    const float* W2    = (const float*)d_in[9];
    const float* b2    = (const float*)d_in[10];
    const float* gamma = (const float*)d_in[11];
    const float* beta  = (const float*)d_in[12];
    float* dout = (float*)d_out;

    // workspace layout
    float* h      = (float*)d_ws;                              // 100000*304 f
    float* bias1p = h + (size_t)N_NODESC*LD;                   // 5*640 f
    float* etab   = bias1p + LAYERS*N1;                        // 5*18*304 f
    float* stats  = etab + LAYERS*18*LD;                       // 640 f
    unsigned short* agg  = (unsigned short*)(stats + 640);     // 100000*320 bf16
    unsigned short* hmid = agg  + (size_t)N_NODESC*K1;         // 100000*640 bf16
    unsigned short* wb1t = hmid + (size_t)N_NODESC*N1;         // 5*640*320 bf16
    unsigned short* wb2t = wb1t + (size_t)LAYERS*N1*K1;        // 5*384*640 bf16
    int*   deg     = (int*)(wb2t + (size_t)LAYERS*N2*K2);
    int*   offs    = deg    + N_NODESC;
    int*   cursor  = offs   + N_NODESC + 1;
    int*   csr_src = cursor + N_NODESC + 1;
    int*   csr_ea  = csr_src + N_EDGESC;
    int*   bsum    = csr_ea + N_EDGESC;
    int*   bpre    = bsum + NB_SCAN;

    const int nb_nf4 = (N_NODESC*LD4 + 255)/256;

    // one-time setup
    k_atom<<<nb_nf4, 256, 0, stream>>>(x, aemb1, aemb2, h);
    k_etab<<<(LAYERS*18*LD4 + 255)/256, 256, 0, stream>>>(eemb1, eemb2, etab);
    k_prepw1<<<(LAYERS*N1*K1 + 255)/256, 256, 0, stream>>>(W1, wb1t);
    k_prepw2<<<(LAYERS*N2*K2 + 255)/256, 256, 0, stream>>>(W2, wb2t);
    k_prepb1<<<(LAYERS*N1 + 255)/256, 256, 0, stream>>>(b1, bias1p);
    k_zero_i<<<(N_NODESC + 255)/256, 256, 0, stream>>>(deg, N_NODESC);
    k_deg<<<(N_EDGESC + 255)/256, 256, 0, stream>>>(ei, deg);
    k_bsum<<<NB_SCAN, 256, 0, stream>>>(deg, bsum);
    k_bscan<<<1, 512, 0, stream>>>(bsum, bpre, offs);
    k_offs<<<NB_SCAN, 256, 0, stream>>>(deg, bpre, offs, cursor);
    k_fill<<<(N_EDGESC + 255)/256, 256, 0, stream>>>(ei, ea, cursor, csr_src, csr_ea);

    const int MT = (N_NODESC + 127)/128;   // 782 M-tiles
    const int nwg1 = 5*MT, nwg2 = 3*MT;
    for(int l=0; l<LAYERS; l++){
        k_agg<<<(N_NODESC*80 + 255)/256, 256, 0, stream>>>(
            h, etab + (size_t)l*18*LD, offs, csr_src, csr_ea, agg);
        k_zero_f<<<(2*EMB + 255)/256, 256, 0, stream>>>(stats, 2*EMB);
        k_mgemm<0, 10, 5><<<nwg1, 256, 0, stream>>>(
            agg, wb1t + (size_t)l*N1*K1, bias1p + (size_t)l*N1,
            hmid, N_NODESC, N1, nullptr, nwg1);
        k_mgemm<1, 20, 3><<<nwg2, 256, 0, stream>>>(
            hmid, wb2t + (size_t)l*N2*K2, b2 + (size_t)l*EMB,
            dout, N_NODESC, EMB, stats, nwg2);
        k_bnapply<<<nb_nf4, 256, 0, stream>>>(dout, stats,
                                              gamma + (size_t)l*EMB, beta + (size_t)l*EMB,
                                              h, dout, (l < LAYERS-1) ? 1 : 0,
                                              (l == LAYERS-1) ? 1 : 0);
    }
}

// Round 7
// 1580.005 us; speedup vs baseline: 1.8011x; 1.0844x over previous
//
#include <hip/hip_runtime.h>
#include <hip/hip_bf16.h>

#define N_NODESC 100000
#define N_EDGESC 250000
#define EMB 300
#define LD 304      // fp32 h / etab stride (float4-friendly)
#define LD4 76
#define LAYERS 5
#define BN_EPS 1e-5f

#define K1 320      // padded K for GEMM1 (agg stride)
#define N1 640      // padded N for GEMM1 (hmid stride, = K for GEMM2)
#define K2 640
#define N2 384      // padded N for GEMM2 (output guarded to 300)

#define NB_SCAN 391 // ceil(100000/256)

typedef __attribute__((ext_vector_type(8))) short short8;
typedef __attribute__((ext_vector_type(4))) float f32x4;

#define GLOAD16(g, l) __builtin_amdgcn_global_load_lds( \
    (const __attribute__((address_space(1))) void*)(g), \
    (__attribute__((address_space(3))) void*)(l), 16, 0, 0)

__device__ __forceinline__ float4 f4add(float4 a, float4 b){
    return make_float4(a.x+b.x, a.y+b.y, a.z+b.z, a.w+b.w);
}
__device__ __forceinline__ unsigned short f2bf(float f){
    __hip_bfloat16 h = __float2bfloat16(f);
    return *(unsigned short*)&h;
}

// ---------------- utility zero kernels --------------------------------------
__global__ void k_zero_i(int* p, int n){
    int i = blockIdx.x*blockDim.x + threadIdx.x;
    if(i < n) p[i] = 0;
}
__global__ void k_zero_f(float* p, int n){
    int i = blockIdx.x*blockDim.x + threadIdx.x;
    if(i < n) p[i] = 0.f;
}

// ---------------- atom encoder: h = emb1[x0] + emb2[x1], fp32 stride LD -----
__global__ void k_atom(const int* __restrict__ x,
                       const float* __restrict__ e1,
                       const float* __restrict__ e2,
                       float* __restrict__ h){
    int idx = blockIdx.x*blockDim.x + threadIdx.x;
    if(idx >= N_NODESC*LD4) return;
    int i = idx / LD4, c = idx % LD4;
    float4 v = make_float4(0,0,0,0);
    if(c < 75){
        int i0 = x[2*i], i1 = x[2*i+1];
        const float4* r1 = (const float4*)(e1 + (size_t)i0*EMB);
        const float4* r2 = (const float4*)(e2 + (size_t)i1*EMB);
        v = f4add(r1[c], r2[c]);
    }
    ((float4*)h)[idx] = v;
}

// ---------------- combined edge-embedding table etab[l][ea0*3+ea1][LD] ------
__global__ void k_etab(const float* __restrict__ e1,
                       const float* __restrict__ e2,
                       float* __restrict__ etab){
    int idx = blockIdx.x*blockDim.x + threadIdx.x;
    if(idx >= LAYERS*18*LD4) return;
    int l = idx / (18*LD4);
    int r = idx % (18*LD4);
    int c = r / LD4, f = r % LD4;
    float4 v = make_float4(0,0,0,0);
    if(f < 75){
        const float4* r1 = (const float4*)(e1 + (size_t)(l*6 + c/3)*EMB);
        const float4* r2 = (const float4*)(e2 + (size_t)(l*3 + c%3)*EMB);
        v = f4add(r1[f], r2[f]);
    }
    ((float4*)etab)[idx] = v;
}

// ---------------- weight prep: B^T padded bf16 ------------------------------
__global__ void k_prepw1(const float* __restrict__ W1, unsigned short* __restrict__ wb){
    int idx = blockIdx.x*blockDim.x + threadIdx.x;
    if(idx >= LAYERS*N1*K1) return;
    int l = idx / (N1*K1);
    int r = idx % (N1*K1);
    int n = r / K1, k = r % K1;
    float v = (n < 600 && k < EMB) ? W1[((size_t)l*EMB + k)*600 + n] : 0.f;
    wb[idx] = f2bf(v);
}
__global__ void k_prepw2(const float* __restrict__ W2, unsigned short* __restrict__ wb){
    int idx = blockIdx.x*blockDim.x + threadIdx.x;
    if(idx >= LAYERS*N2*K2) return;
    int l = idx / (N2*K2);
    int r = idx % (N2*K2);
    int n = r / K2, k = r % K2;
    float v = (n < EMB && k < 600) ? W2[((size_t)l*600 + k)*EMB + n] : 0.f;
    wb[idx] = f2bf(v);
}
__global__ void k_prepb1(const float* __restrict__ b1, float* __restrict__ bp){
    int idx = blockIdx.x*blockDim.x + threadIdx.x;
    if(idx >= LAYERS*N1) return;
    int l = idx / N1, n = idx % N1;
    bp[idx] = (n < 600) ? b1[(size_t)l*600 + n] : 0.f;
}

// ---------------- CSR build -------------------------------------------------
__global__ void k_deg(const int* __restrict__ ei, int* __restrict__ deg){
    int e = blockIdx.x*blockDim.x + threadIdx.x;
    if(e >= N_EDGESC) return;
    atomicAdd(&deg[ei[N_EDGESC + e]], 1);
}

__global__ void k_bsum(const int* __restrict__ deg, int* __restrict__ bsum){
    int g = blockIdx.x*256 + threadIdx.x;
    int v = (g < N_NODESC) ? deg[g] : 0;
    #pragma unroll
    for(int o=32;o>0;o>>=1) v += __shfl_down(v, o);
    __shared__ int sw[4];
    if((threadIdx.x & 63) == 0) sw[threadIdx.x>>6] = v;
    __syncthreads();
    if(threadIdx.x == 0) bsum[blockIdx.x] = sw[0]+sw[1]+sw[2]+sw[3];
}

__global__ void k_bscan(const int* __restrict__ bsum, int* __restrict__ bpre,
                        int* __restrict__ offs){
    __shared__ int sh[512];
    int t = threadIdx.x;
    int v = (t < NB_SCAN) ? bsum[t] : 0;
    sh[t] = v; __syncthreads();
    for(int o=1;o<512;o<<=1){
        int u = (t >= o) ? sh[t-o] : 0;
        __syncthreads();
        sh[t] += u;
        __syncthreads();
    }
    if(t < NB_SCAN) bpre[t] = sh[t] - v;
    if(t == NB_SCAN-1) offs[N_NODESC] = sh[t];
}

__global__ void k_offs(const int* __restrict__ deg, const int* __restrict__ bpre,
                       int* __restrict__ offs, int* __restrict__ cursor){
    __shared__ int sh[256];
    int t = threadIdx.x;
    int g = blockIdx.x*256 + t;
    int v = (g < N_NODESC) ? deg[g] : 0;
    sh[t] = v; __syncthreads();
    for(int o=1;o<256;o<<=1){
        int u = (t >= o) ? sh[t-o] : 0;
        __syncthreads();
        sh[t] += u;
        __syncthreads();
    }
    if(g < N_NODESC){
        int e = bpre[blockIdx.x] + sh[t] - v;
        offs[g] = e; cursor[g] = e;
    }
}

__global__ void k_fill(const int* __restrict__ ei, const int* __restrict__ ea,
                       int* __restrict__ cursor,
                       int* __restrict__ csr_src, int* __restrict__ csr_ea){
    int e = blockIdx.x*blockDim.x + threadIdx.x;
    if(e >= N_EDGESC) return;
    int d = ei[N_EDGESC + e];
    int p = atomicAdd(&cursor[d], 1);
    csr_src[p] = ei[e];
    csr_ea[p]  = ea[2*e]*3 + ea[2*e+1];
}

// ---------------- gather-sum aggregation -> bf16 agg[i][K1] -----------------
__global__ void k_agg(const float* __restrict__ h, const float* __restrict__ etab_l,
                      const int* __restrict__ offs, const int* __restrict__ csr_src,
                      const int* __restrict__ csr_ea, unsigned short* __restrict__ agg){
    int idx = blockIdx.x*blockDim.x + threadIdx.x;
    if(idx >= N_NODESC*80) return;
    int i = idx / 80, c = idx % 80;
    ushort4 out;
    if(c < 75){
        const float4* h4 = (const float4*)h;
        const float4* et = (const float4*)etab_l;
        float4 acc = f4add(h4[(size_t)i*LD4 + c], et[12*LD4 + c]);
        int j0 = offs[i], j1 = offs[i+1];
        for(int j=j0; j<j1; j++){
            int s = csr_src[j];
            int t = csr_ea[j];
            acc = f4add(acc, f4add(h4[(size_t)s*LD4 + c], et[t*LD4 + c]));
        }
        out.x = f2bf(acc.x); out.y = f2bf(acc.y);
        out.z = f2bf(acc.z); out.w = f2bf(acc.w);
    } else {
        out.x = out.y = out.z = out.w = 0;
    }
    *(ushort4*)(agg + (size_t)i*K1 + c*4) = out;
}

// ---------------- bf16 MFMA GEMM: C = epi(A @ Bt^T + bias) ------------------
// 128x128 tile, 4 waves (2x2), BK=32, 3-buffer LDS pipeline with COUNTED
// vmcnt (T4). Per step: {vmcnt(4) lgkmcnt(0); s_barrier; SB(0); issue tile
// kc+2; ds_read; MFMA}.  vmcnt(0) only at the last step.
// ORDERING INVARIANT (fix for R6 race): every STAGE pair must be separated
// by a scheduling fence so vmcnt's in-order count maps 1:1 to tiles. In-loop
// pairs are fenced by the per-step inline asm ("memory"); the PROLOGUE pair
// needs explicit sched_barrier(0) after each STAGE (R6 lacked this -> LLVM
// interleaved tile0/tile1 loads -> vmcnt(4) left tile-0 loads in flight).
// LDS chunk-swizzle phys = logical ^ ((row>>1)&3) on global src + ds_read.
// EPI 0: bf16 LDS-bounce store, +bias, relu.
// EPI 1: BN stats then fp32 LDS-bounce (two 64-row halves), +bias, col<300.
template<int EPI, int KS, int NX>
__global__ __launch_bounds__(256) void k_mgemm(
    const unsigned short* __restrict__ A,
    const unsigned short* __restrict__ Bt,
    const float* __restrict__ bias,
    void* __restrict__ Cptr, int M, int ldc,
    float* __restrict__ stats, int nwg)
{
    __shared__ char smem_c[3*16384 + 512];     // 3 bufs (A 8K | B 8K) + red
    unsigned short* smem_u = (unsigned short*)smem_c;

    // ---- XCD bijective remap, x-major decomposition ------------------------
    int bid = blockIdx.x;
    int q = nwg >> 3, r = nwg & 7;
    int xcd = bid & 7, lo = bid >> 3;
    int wg = (xcd < r) ? (xcd*(q+1) + lo) : (r*(q+1) + (xcd - r)*q + lo);
    int bx = wg % NX, by = wg / NX;
    int m0 = by*128, n0 = bx*128;

    const int tid = threadIdx.x;
    const int wv = tid >> 6, ln = tid & 63;
    const int wm = (wv >> 1)*64, wn = (wv & 1)*64;
    const int lr = ln & 15, hi = ln >> 4;

    // ---- staging addresses (2 chunks per operand per thread) ---------------
    const int id0 = tid, id1 = tid + 256;
    const int rA0 = id0 >> 2, rA1 = id1 >> 2;      // 0..127
    const int c0 = id0 & 3,  c1 = id1 & 3;         // phys chunk
    int g0 = m0 + rA0; if(g0 >= M) g0 = M-1;
    int g1 = m0 + rA1; if(g1 >= M) g1 = M-1;
    const unsigned short* srcA0 = A + (size_t)g0*KS*32 + ((c0 ^ ((rA0>>1)&3))<<3);
    const unsigned short* srcA1 = A + (size_t)g1*KS*32 + ((c1 ^ ((rA1>>1)&3))<<3);
    const unsigned short* srcB0 = Bt + (size_t)(n0 + rA0)*KS*32 + ((c0 ^ ((rA0>>1)&3))<<3);
    const unsigned short* srcB1 = Bt + (size_t)(n0 + rA1)*KS*32 + ((c1 ^ ((rA1>>1)&3))<<3);

    f32x4 acc[4][4] = {};

    // stage tile t into buf t%3
    #define STAGE(t) { \
        char* db_ = smem_c + ((t)%3)*16384; \
        GLOAD16(srcA0 + (t)*32, db_ + id0*16); \
        GLOAD16(srcA1 + (t)*32, db_ + id1*16); \
        GLOAD16(srcB0 + (t)*32, db_ + 8192 + id0*16); \
        GLOAD16(srcB1 + (t)*32, db_ + 8192 + id1*16); }

    // ---- prologue: tiles 0,1 — FENCED so issue order is tile0 then tile1 ---
    STAGE(0)
    __builtin_amdgcn_sched_barrier(0);
    STAGE(1)
    __builtin_amdgcn_sched_barrier(0);

    // per-lane ds_read offsets (ushort units), row-constant across kc
    int offA[4], offB[4];
    #pragma unroll
    for(int m=0;m<4;m++){
        int row = wm + m*16 + lr;
        offA[m] = row*32 + ((hi ^ ((row>>1)&3))<<3);
    }
    #pragma unroll
    for(int n=0;n<4;n++){
        int row = wn + n*16 + lr;
        offB[n] = 4096 + row*32 + ((hi ^ ((row>>1)&3))<<3);
    }

    #pragma unroll
    for(int kc=0; kc<KS; kc++){
        // wait for tile kc (allow tile kc+1's 4 loads to stay in flight)
        if(kc == KS-1) asm volatile("s_waitcnt vmcnt(0) lgkmcnt(0)" ::: "memory");
        else           asm volatile("s_waitcnt vmcnt(4) lgkmcnt(0)" ::: "memory");
        __builtin_amdgcn_s_barrier();
        __builtin_amdgcn_sched_barrier(0);   // keep STAGE strictly after barrier
        if(kc+2 < KS) STAGE(kc+2)
        const unsigned short* bufu = smem_u + (kc%3)*8192;
        short8 av[4], bv[4];
        #pragma unroll
        for(int m=0;m<4;m++) av[m] = *(const short8*)(bufu + offA[m]);
        #pragma unroll
        for(int n=0;n<4;n++) bv[n] = *(const short8*)(bufu + offB[n]);
        #pragma unroll
        for(int m=0;m<4;m++)
            #pragma unroll
            for(int n=0;n<4;n++)
                acc[m][n] = __builtin_amdgcn_mfma_f32_16x16x32_bf16(
                                av[m], bv[n], acc[m][n], 0, 0, 0);
    }
    #undef STAGE

    __syncthreads();   // full drain; LDS free for epilogue reuse

    int rbase = wm + hi*4;
    if(EPI == 0){
        // ---- bounce C tile (bf16) through LDS, coalesced short8 stores -----
        unsigned short* Cs = smem_u;          // [128][128] bf16 = 32 KB
        unsigned short* Cb = (unsigned short*)Cptr;
        #pragma unroll
        for(int n=0;n<4;n++){
            int col = wn + n*16 + lr;
            float bsv = bias[n0 + col];
            #pragma unroll
            for(int m=0;m<4;m++){
                #pragma unroll
                for(int j=0;j<4;j++){
                    int row = rbase + m*16 + j;
                    Cs[row*128 + col] = f2bf(fmaxf(acc[m][n][j] + bsv, 0.f));
                }
            }
        }
        __syncthreads();
        #pragma unroll
        for(int i=0;i<8;i++){
            int id = i*256 + tid;
            int rr = id >> 4, ch = id & 15;
            int gr = m0 + rr;
            if(gr < M)
                *(short8*)(Cb + (size_t)gr*ldc + n0 + ch*8) =
                    *(const short8*)(Cs + rr*128 + ch*8);
        }
    } else {
        // ---- BN stats first, then fp32 LDS bounce in two 64-row halves -----
        float* Cf = (float*)Cptr;
        float* red = (float*)(smem_c + 3*16384);   // 128 floats
        #pragma unroll
        for(int n=0;n<4;n++){
            int col = n0 + wn + n*16 + lr;
            bool cok = (col < EMB);
            float bsv = cok ? bias[col] : 0.f;
            float sS = 0.f, sQ = 0.f;
            #pragma unroll
            for(int m=0;m<4;m++){
                #pragma unroll
                for(int j=0;j<4;j++){
                    int row = m0 + rbase + m*16 + j;
                    if(cok && row < M){
                        float v = acc[m][n][j] + bsv;
                        sS += v; sQ += v*v;
                    }
                }
            }
            sS += __shfl_xor(sS, 16); sQ += __shfl_xor(sQ, 16);
            sS += __shfl_xor(sS, 32); sQ += __shfl_xor(sQ, 32);
            if(hi == 0){ red[(wv*16+lr)*2] = sS; red[(wv*16+lr)*2+1] = sQ; }
            __syncthreads();
            if(wv < 2 && ln < 16){
                float S = red[(wv*16+ln)*2]   + red[((wv+2)*16+ln)*2];
                float Q = red[(wv*16+ln)*2+1] + red[((wv+2)*16+ln)*2+1];
                int c2 = n0 + wv*64 + n*16 + ln;
                if(c2 < EMB){
                    atomicAdd(&stats[c2], S);
                    atomicAdd(&stats[EMB + c2], Q);
                }
            }
            __syncthreads();
        }
        // fp32 bounce: half h covers tile rows [h*64, h*64+64)
        float* Cs = (float*)smem_c;                // [64][128] fp32 = 32 KB
        #pragma unroll
        for(int half=0; half<2; half++){
            if(wm == half*64){
                #pragma unroll
                for(int n=0;n<4;n++){
                    int col = wn + n*16 + lr;
                    float bsv = (n0 + col < EMB) ? bias[n0 + col] : 0.f;
                    #pragma unroll
                    for(int m=0;m<4;m++){
                        #pragma unroll
                        for(int j=0;j<4;j++){
                            int rl = m*16 + hi*4 + j;      // 0..63
                            Cs[rl*128 + col] = acc[m][n][j] + bsv;
                        }
                    }
                }
            }
            __syncthreads();
            #pragma unroll
            for(int i=0;i<8;i++){
                int id = i*256 + tid;
                int rr = id >> 5, c4 = id & 31;
                int col = n0 + c4*4;
                int gr = m0 + half*64 + rr;
                if(col < EMB && gr < M)
                    *(float4*)(Cf + (size_t)gr*ldc + col) =
                        *(const float4*)(Cs + rr*128 + c4*4);
            }
            __syncthreads();
        }
    }
}

// ---------------- BN apply (+relu) ------------------------------------------
__global__ void k_bnapply(const float* __restrict__ X, const float* __restrict__ stats,
                          const float* __restrict__ g, const float* __restrict__ bt,
                          float* __restrict__ hn, float* __restrict__ dout,
                          int relu, int last){
    int idx = blockIdx.x*blockDim.x + threadIdx.x;
    if(idx >= N_NODESC*LD4) return;
    int i = idx / LD4, c = idx % LD4;
    if(c == 75){
        if(!last) ((float4*)hn)[idx] = make_float4(0,0,0,0);
        return;
    }
    const float4* X4 = (const float4*)X;
    float4 v  = X4[(size_t)i*75 + c];
    float4 s  = ((const float4*)stats)[c];
    float4 q  = ((const float4*)stats)[75 + c];
    float4 gg = ((const float4*)g)[c];
    float4 bb = ((const float4*)bt)[c];
    const float inv_n = 1.0f/(float)N_NODESC;
    #define BN1(f) { float m = s.f*inv_n; float var = q.f*inv_n - m*m;          \
                     float r = rsqrtf(var + BN_EPS);                             \
                     v.f = (v.f - m)*r*gg.f + bb.f;                              \
                     if(relu) v.f = fmaxf(v.f, 0.f); }
    BN1(x) BN1(y) BN1(z) BN1(w)
    #undef BN1
    if(last) ((float4*)dout)[(size_t)i*75 + c] = v;
    else     ((float4*)hn)[idx] = v;
}

// ----------------------------------------------------------------------------
extern "C" void kernel_launch(void* const* d_in, const int* in_sizes, int n_in,
                              void* d_out, int out_size, void* d_ws, size_t ws_size,
                              hipStream_t stream) {
    const int*   x     = (const int*)d_in[0];
    const int*   ei    = (const int*)d_in[1];
    const int*   ea    = (const int*)d_in[2];
    const float* aemb1 = (const float*)d_in[3];
    const float* aemb2 = (const float*)d_in[4];
    const float* eemb1 = (const float*)d_in[5];
    const float* eemb2 = (const float*)d_in[6];
    const float* W1    = (const float*)d_in[7];
    const float* b1    = (const float*)d_in[8];
    const float* W2    = (const float*)d_in[9];
    const float* b2    = (const float*)d_in[10];
    const float* gamma = (const float*)d_in[11];
    const float* beta  = (const float*)d_in[12];
    float* dout = (float*)d_out;

    // workspace layout
    float* h      = (float*)d_ws;                              // 100000*304 f
    float* bias1p = h + (size_t)N_NODESC*LD;                   // 5*640 f
    float* etab   = bias1p + LAYERS*N1;                        // 5*18*304 f
    float* stats  = etab + LAYERS*18*LD;                       // 640 f
    unsigned short* agg  = (unsigned short*)(stats + 640);     // 100000*320 bf16
    unsigned short* hmid = agg  + (size_t)N_NODESC*K1;         // 100000*640 bf16
    unsigned short* wb1t = hmid + (size_t)N_NODESC*N1;         // 5*640*320 bf16
    unsigned short* wb2t = wb1t + (size_t)LAYERS*N1*K1;        // 5*384*640 bf16
    int*   deg     = (int*)(wb2t + (size_t)LAYERS*N2*K2);
    int*   offs    = deg    + N_NODESC;
    int*   cursor  = offs   + N_NODESC + 1;
    int*   csr_src = cursor + N_NODESC + 1;
    int*   csr_ea  = csr_src + N_EDGESC;
    int*   bsum    = csr_ea + N_EDGESC;
    int*   bpre    = bsum + NB_SCAN;

    const int nb_nf4 = (N_NODESC*LD4 + 255)/256;

    // one-time setup
    k_atom<<<nb_nf4, 256, 0, stream>>>(x, aemb1, aemb2, h);
    k_etab<<<(LAYERS*18*LD4 + 255)/256, 256, 0, stream>>>(eemb1, eemb2, etab);
    k_prepw1<<<(LAYERS*N1*K1 + 255)/256, 256, 0, stream>>>(W1, wb1t);
    k_prepw2<<<(LAYERS*N2*K2 + 255)/256, 256, 0, stream>>>(W2, wb2t);
    k_prepb1<<<(LAYERS*N1 + 255)/256, 256, 0, stream>>>(b1, bias1p);
    k_zero_i<<<(N_NODESC + 255)/256, 256, 0, stream>>>(deg, N_NODESC);
    k_deg<<<(N_EDGESC + 255)/256, 256, 0, stream>>>(ei, deg);
    k_bsum<<<NB_SCAN, 256, 0, stream>>>(deg, bsum);
    k_bscan<<<1, 512, 0, stream>>>(bsum, bpre, offs);
    k_offs<<<NB_SCAN, 256, 0, stream>>>(deg, bpre, offs, cursor);
    k_fill<<<(N_EDGESC + 255)/256, 256, 0, stream>>>(ei, ea, cursor, csr_src, csr_ea);

    const int MT = (N_NODESC + 127)/128;   // 782 M-tiles
    const int nwg1 = 5*MT, nwg2 = 3*MT;
    for(int l=0; l<LAYERS; l++){
        k_agg<<<(N_NODESC*80 + 255)/256, 256, 0, stream>>>(
            h, etab + (size_t)l*18*LD, offs, csr_src, csr_ea, agg);
        k_zero_f<<<(2*EMB + 255)/256, 256, 0, stream>>>(stats, 2*EMB);
        k_mgemm<0, 10, 5><<<nwg1, 256, 0, stream>>>(
            agg, wb1t + (size_t)l*N1*K1, bias1p + (size_t)l*N1,
            hmid, N_NODESC, N1, nullptr, nwg1);
        k_mgemm<1, 20, 3><<<nwg2, 256, 0, stream>>>(
            hmid, wb2t + (size_t)l*N2*K2, b2 + (size_t)l*EMB,
            dout, N_NODESC, EMB, stats, nwg2);
        k_bnapply<<<nb_nf4, 256, 0, stream>>>(dout, stats,
                                              gamma + (size_t)l*EMB, beta + (size_t)l*EMB,
                                              h, dout, (l < LAYERS-1) ? 1 : 0,
                                              (l == LAYERS-1) ? 1 : 0);
    }
}

// Round 8
// 1347.967 us; speedup vs baseline: 2.1111x; 1.1721x over previous
//
#include <hip/hip_runtime.h>
#include <hip/hip_bf16.h>

#define N_NODESC 100000
#define N_EDGESC 250000
#define EMB 300
#define LD 304      // fp32 h stride (float4-friendly)
#define LD4 76
#define LAYERS 5
#define BN_EPS 1e-5f

#define K1 320      // padded K for GEMM1 (agg stride)
#define N1 640      // padded N for GEMM1 (hmid stride, = K for GEMM2)
#define K2 640
#define N2 384      // padded N for GEMM2 (output guarded to 300)

#define NB_SCAN 391 // ceil(100000/256)

typedef __attribute__((ext_vector_type(8))) short short8;
typedef __attribute__((ext_vector_type(4))) float f32x4;

#define GLOAD16(g, l) __builtin_amdgcn_global_load_lds( \
    (const __attribute__((address_space(1))) void*)(g), \
    (__attribute__((address_space(3))) void*)(l), 16, 0, 0)

__device__ __forceinline__ float4 f4add(float4 a, float4 b){
    return make_float4(a.x+b.x, a.y+b.y, a.z+b.z, a.w+b.w);
}
__device__ __forceinline__ unsigned short f2bf(float f){
    __hip_bfloat16 h = __float2bfloat16(f);
    return *(unsigned short*)&h;
}

// ---------------- utility zero kernels --------------------------------------
__global__ void k_zero_i(int* p, int n){
    int i = blockIdx.x*blockDim.x + threadIdx.x;
    if(i < n) p[i] = 0;
}
__global__ void k_zero_f(float* p, int n){
    int i = blockIdx.x*blockDim.x + threadIdx.x;
    if(i < n) p[i] = 0.f;
}

// ---------------- atom encoder: h = emb1[x0] + emb2[x1], fp32 stride LD -----
__global__ void k_atom(const int* __restrict__ x,
                       const float* __restrict__ e1,
                       const float* __restrict__ e2,
                       float* __restrict__ h){
    int idx = blockIdx.x*blockDim.x + threadIdx.x;
    if(idx >= N_NODESC*LD4) return;
    int i = idx / LD4, c = idx % LD4;
    float4 v = make_float4(0,0,0,0);
    if(c < 75){
        int i0 = x[2*i], i1 = x[2*i+1];
        const float4* r1 = (const float4*)(e1 + (size_t)i0*EMB);
        const float4* r2 = (const float4*)(e2 + (size_t)i1*EMB);
        v = f4add(r1[c], r2[c]);
    }
    ((float4*)h)[idx] = v;
}

// ---------------- combined edge-embedding table etab[l][ea0*3+ea1][LD] ------
__global__ void k_etab(const float* __restrict__ e1,
                       const float* __restrict__ e2,
                       float* __restrict__ etab){
    int idx = blockIdx.x*blockDim.x + threadIdx.x;
    if(idx >= LAYERS*18*LD4) return;
    int l = idx / (18*LD4);
    int r = idx % (18*LD4);
    int c = r / LD4, f = r % LD4;
    float4 v = make_float4(0,0,0,0);
    if(f < 75){
        const float4* r1 = (const float4*)(e1 + (size_t)(l*6 + c/3)*EMB);
        const float4* r2 = (const float4*)(e2 + (size_t)(l*3 + c%3)*EMB);
        v = f4add(r1[f], r2[f]);
    }
    ((float4*)etab)[idx] = v;
}

// ---------------- weight prep: B^T padded bf16 ------------------------------
__global__ void k_prepw1(const float* __restrict__ W1, unsigned short* __restrict__ wb){
    int idx = blockIdx.x*blockDim.x + threadIdx.x;
    if(idx >= LAYERS*N1*K1) return;
    int l = idx / (N1*K1);
    int r = idx % (N1*K1);
    int n = r / K1, k = r % K1;
    float v = (n < 600 && k < EMB) ? W1[((size_t)l*EMB + k)*600 + n] : 0.f;
    wb[idx] = f2bf(v);
}
__global__ void k_prepw2(const float* __restrict__ W2, unsigned short* __restrict__ wb){
    int idx = blockIdx.x*blockDim.x + threadIdx.x;
    if(idx >= LAYERS*N2*K2) return;
    int l = idx / (N2*K2);
    int r = idx % (N2*K2);
    int n = r / K2, k = r % K2;
    float v = (n < EMB && k < 600) ? W2[((size_t)l*600 + k)*EMB + n] : 0.f;
    wb[idx] = f2bf(v);
}
__global__ void k_prepb1(const float* __restrict__ b1, float* __restrict__ bp){
    int idx = blockIdx.x*blockDim.x + threadIdx.x;
    if(idx >= LAYERS*N1) return;
    int l = idx / N1, n = idx % N1;
    bp[idx] = (n < 600) ? b1[(size_t)l*600 + n] : 0.f;
}

// ---------------- CSR build -------------------------------------------------
__global__ void k_deg(const int* __restrict__ ei, int* __restrict__ deg){
    int e = blockIdx.x*blockDim.x + threadIdx.x;
    if(e >= N_EDGESC) return;
    atomicAdd(&deg[ei[N_EDGESC + e]], 1);
}

__global__ void k_bsum(const int* __restrict__ deg, int* __restrict__ bsum){
    int g = blockIdx.x*256 + threadIdx.x;
    int v = (g < N_NODESC) ? deg[g] : 0;
    #pragma unroll
    for(int o=32;o>0;o>>=1) v += __shfl_down(v, o);
    __shared__ int sw[4];
    if((threadIdx.x & 63) == 0) sw[threadIdx.x>>6] = v;
    __syncthreads();
    if(threadIdx.x == 0) bsum[blockIdx.x] = sw[0]+sw[1]+sw[2]+sw[3];
}

__global__ void k_bscan(const int* __restrict__ bsum, int* __restrict__ bpre,
                        int* __restrict__ offs){
    __shared__ int sh[512];
    int t = threadIdx.x;
    int v = (t < NB_SCAN) ? bsum[t] : 0;
    sh[t] = v; __syncthreads();
    for(int o=1;o<512;o<<=1){
        int u = (t >= o) ? sh[t-o] : 0;
        __syncthreads();
        sh[t] += u;
        __syncthreads();
    }
    if(t < NB_SCAN) bpre[t] = sh[t] - v;
    if(t == NB_SCAN-1) offs[N_NODESC] = sh[t];
}

__global__ void k_offs(const int* __restrict__ deg, const int* __restrict__ bpre,
                       int* __restrict__ offs, int* __restrict__ cursor){
    __shared__ int sh[256];
    int t = threadIdx.x;
    int g = blockIdx.x*256 + t;
    int v = (g < N_NODESC) ? deg[g] : 0;
    sh[t] = v; __syncthreads();
    for(int o=1;o<256;o<<=1){
        int u = (t >= o) ? sh[t-o] : 0;
        __syncthreads();
        sh[t] += u;
        __syncthreads();
    }
    if(g < N_NODESC){
        int e = bpre[blockIdx.x] + sh[t] - v;
        offs[g] = e; cursor[g] = e;
    }
}

__global__ void k_fill(const int* __restrict__ ei, const int* __restrict__ ea,
                       int* __restrict__ cursor,
                       int* __restrict__ csr_src, int* __restrict__ csr_ea){
    int e = blockIdx.x*blockDim.x + threadIdx.x;
    if(e >= N_EDGESC) return;
    int d = ei[N_EDGESC + e];
    int p = atomicAdd(&cursor[d], 1);
    csr_src[p] = ei[e];
    csr_ea[p]  = ea[2*e]*3 + ea[2*e+1];
}

// ---------------- gather-sum aggregation -> bf16 agg[i][K1] -----------------
// BN=0: src = h (stride LD4 float4), plain gather (layer 0).
// BN=1: src = dout (stride 75 float4); per element apply relu(a*x+b) where
//       a,b are the BN affine params of the PREVIOUS layer (aff[0..74]=a4,
//       aff[75..149]=b4). Values identical to materializing bnapply+h.
template<int BN>
__global__ void k_aggT(const float* __restrict__ src, const float* __restrict__ etab_l,
                       const float* __restrict__ aff,
                       const int* __restrict__ offs, const int* __restrict__ csr_src,
                       const int* __restrict__ csr_ea, unsigned short* __restrict__ agg){
    int idx = blockIdx.x*blockDim.x + threadIdx.x;
    if(idx >= N_NODESC*80) return;
    int i = idx / 80, c = idx % 80;
    ushort4 out;
    if(c < 75){
        const float4* s4 = (const float4*)src;
        const float4* et = (const float4*)etab_l;
        const int stride = BN ? 75 : LD4;
        float4 a4, b4;
        if(BN){ a4 = ((const float4*)aff)[c]; b4 = ((const float4*)aff)[75 + c]; }
        #define LOADV(s_, v_) { float4 x_ = s4[(size_t)(s_)*stride + c];          \
            if(BN){ v_.x = fmaxf(fmaf(x_.x,a4.x,b4.x),0.f);                       \
                    v_.y = fmaxf(fmaf(x_.y,a4.y,b4.y),0.f);                       \
                    v_.z = fmaxf(fmaf(x_.z,a4.z,b4.z),0.f);                       \
                    v_.w = fmaxf(fmaf(x_.w,a4.w,b4.w),0.f); } else v_ = x_; }
        float4 v;
        LOADV(i, v)
        float4 acc = f4add(v, et[12*LD4 + c]);   // self loop, attr idx 12
        int j0 = offs[i], j1 = offs[i+1];
        for(int j=j0; j<j1; j++){
            int s = csr_src[j];
            int t = csr_ea[j];
            LOADV(s, v)
            acc = f4add(acc, f4add(v, et[t*LD4 + c]));
        }
        #undef LOADV
        out.x = f2bf(acc.x); out.y = f2bf(acc.y);
        out.z = f2bf(acc.z); out.w = f2bf(acc.w);
    } else {
        out.x = out.y = out.z = out.w = 0;
    }
    *(ushort4*)(agg + (size_t)i*K1 + c*4) = out;
}

// ---------------- BN affine precompute: a = g*rsqrt(var+eps), b = bt - m*a --
__global__ void k_bnaff(const float* __restrict__ stats, const float* __restrict__ g,
                        const float* __restrict__ bt, float* __restrict__ aff){
    int c = blockIdx.x*blockDim.x + threadIdx.x;
    if(c >= EMB) return;
    const float inv_n = 1.0f/(float)N_NODESC;
    float m = stats[c]*inv_n;
    float var = stats[EMB + c]*inv_n - m*m;
    float a = g[c]*rsqrtf(var + BN_EPS);
    aff[c] = a;
    aff[EMB + c] = bt[c] - m*a;
}

// ---------------- bf16 MFMA GEMM: C = epi(A @ Bt^T + bias) ------------------
// 128x128 tile, 8 waves (2M x 4N wave grid, wave tile 64x32), 512 threads,
// BK=32, 3-buffer LDS + counted vmcnt pipeline (T4): per step
// {vmcnt(2) lgkmcnt(0); s_barrier; sched_barrier(0); STAGE(kc+2); ds_read;
//  setprio(1); 8 MFMA; setprio(0)}.  vmcnt(0) only at the last step.
// Prologue STAGEs fenced with sched_barrier(0) (R6 lesson: issue order must
// match vmcnt accounting).  LDS chunk-swizzle phys = logical ^ ((row>>1)&3)
// on global src + ds_read.  Epilogue bounces padded (strides 144/132) to
// avoid bank conflicts.
// EPI 0: bf16 LDS-bounce store, +bias, relu.
// EPI 1: fused BN stats then fp32 LDS-bounce (two 64-row halves), col<300.
template<int EPI, int KS, int NX>
__global__ __launch_bounds__(512) void k_mgemm(
    const unsigned short* __restrict__ A,
    const unsigned short* __restrict__ Bt,
    const float* __restrict__ bias,
    void* __restrict__ Cptr, int M, int ldc,
    float* __restrict__ stats, int nwg)
{
    __shared__ char smem_c[3*16384 + 1024];    // 3 bufs (A 8K | B 8K) + red
    unsigned short* smem_u = (unsigned short*)smem_c;

    // ---- XCD bijective remap, x-major decomposition ------------------------
    int bid = blockIdx.x;
    int q = nwg >> 3, r = nwg & 7;
    int xcd = bid & 7, lo = bid >> 3;
    int wg = (xcd < r) ? (xcd*(q+1) + lo) : (r*(q+1) + (xcd - r)*q + lo);
    int bx = wg % NX, by = wg / NX;
    int m0 = by*128, n0 = bx*128;

    const int tid = threadIdx.x;
    const int wv = tid >> 6, ln = tid & 63;
    const int wvm = wv >> 2, wvn = wv & 3;     // wave tile: rows wvm*64, cols wvn*32
    const int lr = ln & 15, hi = ln >> 4;

    // ---- staging: 1 chunk of A + 1 of B per thread per tile ----------------
    const int rS = tid >> 2, cS = tid & 3;     // row 0..127, phys chunk 0..3
    int gA = m0 + rS; if(gA >= M) gA = M-1;
    const unsigned short* srcA = A  + (size_t)gA*(KS*32)      + ((cS ^ ((rS>>1)&3))<<3);
    const unsigned short* srcB = Bt + (size_t)(n0 + rS)*(KS*32) + ((cS ^ ((rS>>1)&3))<<3);

    f32x4 acc[4][2] = {};

    // stage tile t into buf t%3 (2 loads/thread -> vmcnt counts 2 per tile)
    #define STAGE(t) { \
        char* db_ = smem_c + ((t)%3)*16384; \
        GLOAD16(srcA + (t)*32, db_ + tid*16); \
        GLOAD16(srcB + (t)*32, db_ + 8192 + tid*16); }

    // ---- prologue: tiles 0,1 — fenced so issue order matches vmcnt ---------
    STAGE(0)
    __builtin_amdgcn_sched_barrier(0);
    STAGE(1)
    __builtin_amdgcn_sched_barrier(0);

    // per-lane ds_read offsets (ushort units), row-constant across kc
    int offA[4], offB[2];
    #pragma unroll
    for(int m=0;m<4;m++){
        int row = wvm*64 + m*16 + lr;
        offA[m] = row*32 + ((hi ^ ((row>>1)&3))<<3);
    }
    #pragma unroll
    for(int n=0;n<2;n++){
        int brow = wvn*32 + n*16 + lr;
        offB[n] = 4096 + brow*32 + ((hi ^ ((brow>>1)&3))<<3);
    }

    #pragma unroll
    for(int kc=0; kc<KS; kc++){
        // wait for tile kc (allow tile kc+1's 2 loads to stay in flight)
        if(kc == KS-1) asm volatile("s_waitcnt vmcnt(0) lgkmcnt(0)" ::: "memory");
        else           asm volatile("s_waitcnt vmcnt(2) lgkmcnt(0)" ::: "memory");
        __builtin_amdgcn_s_barrier();
        __builtin_amdgcn_sched_barrier(0);   // keep STAGE strictly after barrier
        if(kc+2 < KS) STAGE(kc+2)
        const unsigned short* bufu = smem_u + (kc%3)*8192;
        short8 av[4], bv[2];
        #pragma unroll
        for(int m=0;m<4;m++) av[m] = *(const short8*)(bufu + offA[m]);
        #pragma unroll
        for(int n=0;n<2;n++) bv[n] = *(const short8*)(bufu + offB[n]);
        __builtin_amdgcn_s_setprio(1);
        #pragma unroll
        for(int m=0;m<4;m++)
            #pragma unroll
            for(int n=0;n<2;n++)
                acc[m][n] = __builtin_amdgcn_mfma_f32_16x16x32_bf16(
                                av[m], bv[n], acc[m][n], 0, 0, 0);
        __builtin_amdgcn_s_setprio(0);
    }
    #undef STAGE

    __syncthreads();   // full drain; LDS free for epilogue reuse

    if(EPI == 0){
        // ---- bounce C tile (bf16) through LDS (stride 144), short8 stores --
        unsigned short* Cs = smem_u;          // [128][144] = 36,864 B
        unsigned short* Cb = (unsigned short*)Cptr;
        #pragma unroll
        for(int n=0;n<2;n++){
            int col = wvn*32 + n*16 + lr;
            float bsv = bias[n0 + col];
            #pragma unroll
            for(int m=0;m<4;m++){
                #pragma unroll
                for(int j=0;j<4;j++){
                    int row = wvm*64 + m*16 + hi*4 + j;
                    Cs[row*144 + col] = f2bf(fmaxf(acc[m][n][j] + bsv, 0.f));
                }
            }
        }
        __syncthreads();
        #pragma unroll
        for(int i=0;i<4;i++){
            int id = i*512 + tid;
            int rr = id >> 4, ch = id & 15;
            int gr = m0 + rr;
            if(gr < M)
                *(short8*)(Cb + (size_t)gr*ldc + n0 + ch*8) =
                    *(const short8*)(Cs + rr*144 + ch*8);
        }
    } else {
        // ---- fused BN stats, then fp32 LDS bounce (stride 132) -------------
        float* Cf = (float*)Cptr;
        float* red = (float*)(smem_c + 3*16384);   // 256 floats
        #pragma unroll
        for(int n=0;n<2;n++){
            int col = n0 + wvn*32 + n*16 + lr;
            bool cok = (col < EMB);
            float bsv = cok ? bias[col] : 0.f;
            float sS = 0.f, sQ = 0.f;
            #pragma unroll
            for(int m=0;m<4;m++){
                #pragma unroll
                for(int j=0;j<4;j++){
                    int row = m0 + wvm*64 + m*16 + hi*4 + j;
                    if(cok && row < M){
                        float v = acc[m][n][j] + bsv;
                        sS += v; sQ += v*v;
                    }
                }
            }
            sS += __shfl_xor(sS, 16); sQ += __shfl_xor(sQ, 16);
            sS += __shfl_xor(sS, 32); sQ += __shfl_xor(sQ, 32);
            if(hi == 0){ red[(wv*16+lr)*2] = sS; red[(wv*16+lr)*2+1] = sQ; }
            __syncthreads();
            if(wv < 4 && ln < 16){
                float S = red[(wv*16+ln)*2]   + red[((wv+4)*16+ln)*2];
                float Q = red[(wv*16+ln)*2+1] + red[((wv+4)*16+ln)*2+1];
                int c2 = n0 + wv*32 + n*16 + ln;
                if(c2 < EMB){
                    atomicAdd(&stats[c2], S);
                    atomicAdd(&stats[EMB + c2], Q);
                }
            }
            __syncthreads();
        }
        // fp32 bounce: half covers tile rows [half*64, half*64+64)
        float* Cs = (float*)smem_c;                // [64][132] = 33,792 B
        #pragma unroll
        for(int half=0; half<2; half++){
            if(wvm == half){
                #pragma unroll
                for(int n=0;n<2;n++){
                    int col = wvn*32 + n*16 + lr;
                    float bsv = (n0 + col < EMB) ? bias[n0 + col] : 0.f;
                    #pragma unroll
                    for(int m=0;m<4;m++){
                        #pragma unroll
                        for(int j=0;j<4;j++){
                            int rl = m*16 + hi*4 + j;      // 0..63
                            Cs[rl*132 + col] = acc[m][n][j] + bsv;
                        }
                    }
                }
            }
            __syncthreads();
            #pragma unroll
            for(int i=0;i<4;i++){
                int id = i*512 + tid;
                int rr = id >> 5, c4 = id & 31;
                int col = n0 + c4*4;
                int gr = m0 + half*64 + rr;
                if(col < EMB && gr < M)
                    *(float4*)(Cf + (size_t)gr*ldc + col) =
                        *(const float4*)(Cs + rr*132 + c4*4);
            }
            __syncthreads();
        }
    }
}

// ---------------- BN apply (final layer only: no relu, writes dout) ---------
__global__ void k_bnapply(const float* __restrict__ X, const float* __restrict__ stats,
                          const float* __restrict__ g, const float* __restrict__ bt,
                          float* __restrict__ dout){
    int idx = blockIdx.x*blockDim.x + threadIdx.x;
    if(idx >= N_NODESC*75) return;
    int i = idx / 75, c = idx % 75;
    const float4* X4 = (const float4*)X;
    float4 v  = X4[(size_t)i*75 + c];
    float4 s  = ((const float4*)stats)[c];
    float4 q  = ((const float4*)stats)[75 + c];
    float4 gg = ((const float4*)g)[c];
    float4 bb = ((const float4*)bt)[c];
    const float inv_n = 1.0f/(float)N_NODESC;
    #define BN1(f) { float m = s.f*inv_n; float var = q.f*inv_n - m*m;          \
                     float r = rsqrtf(var + BN_EPS);                             \
                     v.f = (v.f - m)*r*gg.f + bb.f; }
    BN1(x) BN1(y) BN1(z) BN1(w)
    #undef BN1
    ((float4*)dout)[(size_t)i*75 + c] = v;
}

// ----------------------------------------------------------------------------
extern "C" void kernel_launch(void* const* d_in, const int* in_sizes, int n_in,
                              void* d_out, int out_size, void* d_ws, size_t ws_size,
                              hipStream_t stream) {
    const int*   x     = (const int*)d_in[0];
    const int*   ei    = (const int*)d_in[1];
    const int*   ea    = (const int*)d_in[2];
    const float* aemb1 = (const float*)d_in[3];
    const float* aemb2 = (const float*)d_in[4];
    const float* eemb1 = (const float*)d_in[5];
    const float* eemb2 = (const float*)d_in[6];
    const float* W1    = (const float*)d_in[7];
    const float* b1    = (const float*)d_in[8];
    const float* W2    = (const float*)d_in[9];
    const float* b2    = (const float*)d_in[10];
    const float* gamma = (const float*)d_in[11];
    const float* beta  = (const float*)d_in[12];
    float* dout = (float*)d_out;

    // workspace layout
    float* h      = (float*)d_ws;                              // 100000*304 f
    float* bias1p = h + (size_t)N_NODESC*LD;                   // 5*640 f
    float* etab   = bias1p + LAYERS*N1;                        // 5*18*304 f
    float* stats  = etab + LAYERS*18*LD;                       // 640 f
    float* aff    = stats + 640;                               // 640 f
    unsigned short* agg  = (unsigned short*)(aff + 640);       // 100000*320 bf16
    unsigned short* hmid = agg  + (size_t)N_NODESC*K1;         // 100000*640 bf16
    unsigned short* wb1t = hmid + (size_t)N_NODESC*N1;         // 5*640*320 bf16
    unsigned short* wb2t = wb1t + (size_t)LAYERS*N1*K1;        // 5*384*640 bf16
    int*   deg     = (int*)(wb2t + (size_t)LAYERS*N2*K2);
    int*   offs    = deg    + N_NODESC;
    int*   cursor  = offs   + N_NODESC + 1;
    int*   csr_src = cursor + N_NODESC + 1;
    int*   csr_ea  = csr_src + N_EDGESC;
    int*   bsum    = csr_ea + N_EDGESC;
    int*   bpre    = bsum + NB_SCAN;

    const int nb_nf4 = (N_NODESC*LD4 + 255)/256;

    // one-time setup
    k_atom<<<nb_nf4, 256, 0, stream>>>(x, aemb1, aemb2, h);
    k_etab<<<(LAYERS*18*LD4 + 255)/256, 256, 0, stream>>>(eemb1, eemb2, etab);
    k_prepw1<<<(LAYERS*N1*K1 + 255)/256, 256, 0, stream>>>(W1, wb1t);
    k_prepw2<<<(LAYERS*N2*K2 + 255)/256, 256, 0, stream>>>(W2, wb2t);
    k_prepb1<<<(LAYERS*N1 + 255)/256, 256, 0, stream>>>(b1, bias1p);
    k_zero_i<<<(N_NODESC + 255)/256, 256, 0, stream>>>(deg, N_NODESC);
    k_deg<<<(N_EDGESC + 255)/256, 256, 0, stream>>>(ei, deg);
    k_bsum<<<NB_SCAN, 256, 0, stream>>>(deg, bsum);
    k_bscan<<<1, 512, 0, stream>>>(bsum, bpre, offs);
    k_offs<<<NB_SCAN, 256, 0, stream>>>(deg, bpre, offs, cursor);
    k_fill<<<(N_EDGESC + 255)/256, 256, 0, stream>>>(ei, ea, cursor, csr_src, csr_ea);

    const int MT = (N_NODESC + 127)/128;   // 782 M-tiles
    const int nwg1 = 5*MT, nwg2 = 3*MT;
    const int nb_agg = (N_NODESC*80 + 255)/256;
    for(int l=0; l<LAYERS; l++){
        if(l == 0)
            k_aggT<0><<<nb_agg, 256, 0, stream>>>(
                h, etab, stats /*unused*/, offs, csr_src, csr_ea, agg);
        else
            k_aggT<1><<<nb_agg, 256, 0, stream>>>(
                dout, etab + (size_t)l*18*LD, aff, offs, csr_src, csr_ea, agg);
        k_zero_f<<<(2*EMB + 255)/256, 256, 0, stream>>>(stats, 2*EMB);
        k_mgemm<0, 10, 5><<<nwg1, 512, 0, stream>>>(
            agg, wb1t + (size_t)l*N1*K1, bias1p + (size_t)l*N1,
            hmid, N_NODESC, N1, nullptr, nwg1);
        k_mgemm<1, 20, 3><<<nwg2, 512, 0, stream>>>(
            hmid, wb2t + (size_t)l*N2*K2, b2 + (size_t)l*EMB,
            dout, N_NODESC, EMB, stats, nwg2);
        if(l < LAYERS-1)
            k_bnaff<<<2, 256, 0, stream>>>(stats, gamma + (size_t)l*EMB,
                                           beta + (size_t)l*EMB, aff);
        else
            k_bnapply<<<(N_NODESC*75 + 255)/256, 256, 0, stream>>>(
                dout, stats, gamma + (size_t)l*EMB, beta + (size_t)l*EMB, dout);
    }
}